// Round 5
// baseline (532.977 us; speedup 1.0000x reference)
//
#include <hip/hip_runtime.h>

// ---------------- problem constants ----------------
#define N0 262144
#define N1 32768
#define N2 4096
#define EPSBN 1e-5f

// ---------------- conv kernel (pure gather-GEMM; input already activated) ----------------
// Each thread computes R output rows (m = base + r*256), DTILE output channels.
// partial p=kg: ypart[kg][m, dg*DTILE+d] = sum_{t in tap group kg} sum_c x[neigh[m,kg*TAPS+t], c] * W[kg*TAPS+t, c, dg*DTILE+d]
template<int K, int CIN, int COUT, int TAPS, int DTILE, int KG, int DG, int R, bool FIRST>
__global__ __launch_bounds__(256) void conv_kernel(
    const float* __restrict__ x,         // [Nin, CIN] (FIRST: raw input, CIN=3)
    const int*   __restrict__ neigh,     // [M, K]
    const float* __restrict__ W,         // [K, CIN, COUT] f32
    float*       __restrict__ yout,      // KG==1: [M,COUT]; KG>1: partial base
    size_t       ystride,                // elements between partial buffers
    int M)
{
    static_assert(K == TAPS * KG, "k split");
    static_assert(COUT == DTILE * DG, "d split");
    constexpr int WSZ = TAPS * CIN * DTILE;
    __shared__ __align__(16) float Wl[WSZ];

    const int tid = threadIdx.x;
    const int kg = blockIdx.y, dg = blockIdx.z;

    // vectorized float4 weight staging: Wl[(t*CIN+c)*DTILE + d]
    for (int i4 = tid; i4 < WSZ / 4; i4 += 256) {
        const int d4 = i4 % (DTILE / 4);
        const int rc = i4 / (DTILE / 4);            // t*CIN + c
        const float4* src = (const float4*)(W + ((size_t)kg * TAPS * CIN + rc) * COUT + dg * DTILE);
        ((float4*)Wl)[i4] = src[d4];
    }
    __syncthreads();

    const int base = blockIdx.x * (256 * R) + tid;   // rows: base + r*256 (all grids exact)

    float acc[R][DTILE];
#pragma unroll
    for (int r = 0; r < R; ++r)
#pragma unroll
        for (int d = 0; d < DTILE; ++d) acc[r][d] = 0.f;

    if constexpr (FIRST) {
        // CIN == 3, tap batches of 3 to bound staging registers
        for (int tg = 0; tg < TAPS; tg += 3) {
            int id[3][R];
#pragma unroll
            for (int u = 0; u < 3; ++u)
#pragma unroll
                for (int r = 0; r < R; ++r)
                    id[u][r] = neigh[(size_t)(base + r * 256) * K + tg + u];
            float xs[3][R][3];
#pragma unroll
            for (int u = 0; u < 3; ++u)
#pragma unroll
                for (int r = 0; r < R; ++r) {
                    const float* xp = x + (size_t)id[u][r] * 3;
                    xs[u][r][0] = xp[0]; xs[u][r][1] = xp[1]; xs[u][r][2] = xp[2];
                }
#pragma unroll
            for (int u = 0; u < 3; ++u)
#pragma unroll
                for (int c = 0; c < 3; ++c) {
                    const float4* wrow = (const float4*)&Wl[((tg + u) * 3 + c) * DTILE];
#pragma unroll
                    for (int d4 = 0; d4 < DTILE / 4; ++d4) {
                        float4 w = wrow[d4];
#pragma unroll
                        for (int r = 0; r < R; ++r) {
                            const float a = xs[u][r][c];
                            acc[r][4 * d4 + 0] += a * w.x;
                            acc[r][4 * d4 + 1] += a * w.y;
                            acc[r][4 * d4 + 2] += a * w.z;
                            acc[r][4 * d4 + 3] += a * w.w;
                        }
                    }
                }
        }
    } else {
        // prefetch all tap indices (TAPS <= 9)
        int idxs[TAPS][R];
#pragma unroll
        for (int t = 0; t < TAPS; ++t)
#pragma unroll
            for (int r = 0; r < R; ++r)
                idxs[t][r] = neigh[(size_t)(base + r * 256) * K + kg * TAPS + t];

        constexpr int CHUNK = 12;   // 3 float4 per row per chunk
        for (int t = 0; t < TAPS; ++t) {
            const float* xr[R];
#pragma unroll
            for (int r = 0; r < R; ++r) xr[r] = x + (size_t)idxs[t][r] * CIN;
#pragma unroll
            for (int cc = 0; cc < CIN / CHUNK; ++cc) {
                float xv[R][CHUNK];
#pragma unroll
                for (int r = 0; r < R; ++r)
#pragma unroll
                    for (int j = 0; j < CHUNK / 4; ++j)
                        ((float4*)xv[r])[j] = ((const float4*)xr[r])[cc * (CHUNK / 4) + j];
#pragma unroll
                for (int jc = 0; jc < CHUNK; ++jc) {
                    const int c = cc * CHUNK + jc;
                    const float4* wrow = (const float4*)&Wl[(t * CIN + c) * DTILE];
#pragma unroll
                    for (int d4 = 0; d4 < DTILE / 4; ++d4) {
                        float4 w = wrow[d4];
#pragma unroll
                        for (int r = 0; r < R; ++r) {
                            const float a = xv[r][jc];
                            acc[r][4 * d4 + 0] += a * w.x;
                            acc[r][4 * d4 + 1] += a * w.y;
                            acc[r][4 * d4 + 2] += a * w.z;
                            acc[r][4 * d4 + 3] += a * w.w;
                        }
                    }
                }
            }
        }
    }

#pragma unroll
    for (int r = 0; r < R; ++r) {
        const int m = base + r * 256;
        float* yo = (KG > 1)
            ? yout + (size_t)kg * ystride + (size_t)m * COUT + dg * DTILE
            : yout + (size_t)m * COUT + dg * DTILE;
#pragma unroll
        for (int d4 = 0; d4 < DTILE / 4; ++d4) {
            ((float4*)yo)[d4] = make_float4(acc[r][4 * d4 + 0], acc[r][4 * d4 + 1],
                                            acc[r][4 * d4 + 2], acc[r][4 * d4 + 3]);
        }
    }
}

// ---------------- stats: sum P partials -> yfull, column sum/sumsq, fused finalize ----------------
template<int C, int R, int P, bool WRITE_Y>
__global__ void stats_kernel(const float* __restrict__ part, size_t pstride,
                             float* __restrict__ yfull, int M,
                             const float* __restrict__ gamma_, const float* __restrict__ beta_,
                             float* __restrict__ sums, int* __restrict__ counter,
                             float* __restrict__ ss_out)
{
    __shared__ float ls[R][C];
    __shared__ float lq[R][C];
    __shared__ int lastflag;

    const int c = threadIdx.x;   // [0, C)
    const int ty = threadIdx.y;  // [0, R)

    float s = 0.f, q = 0.f;
    for (int r = blockIdx.x * R + ty; r < M; r += gridDim.x * R) {
        const size_t off = (size_t)r * C + c;
        float v = 0.f;
#pragma unroll
        for (int p = 0; p < P; ++p) v += part[(size_t)p * pstride + off];
        if constexpr (WRITE_Y) yfull[off] = v;
        s += v;
        q += v * v;
    }
    ls[ty][c] = s; lq[ty][c] = q;
    __syncthreads();
    if (ty == 0) {
#pragma unroll
        for (int r = 1; r < R; ++r) { s += ls[r][c]; q += lq[r][c]; }
        atomicAdd(&sums[c], s);
        atomicAdd(&sums[C + c], q);
    }
    __syncthreads();
    if (c == 0 && ty == 0) {
        __threadfence();
        int p = __hip_atomic_fetch_add(counter, 1, __ATOMIC_ACQ_REL, __HIP_MEMORY_SCOPE_AGENT);
        lastflag = (p == (int)gridDim.x - 1) ? 1 : 0;
    }
    __syncthreads();
    if (lastflag && ty == 0) {
        float S = __hip_atomic_load(&sums[c],     __ATOMIC_RELAXED, __HIP_MEMORY_SCOPE_AGENT);
        float Q = __hip_atomic_load(&sums[C + c], __ATOMIC_RELAXED, __HIP_MEMORY_SCOPE_AGENT);
        float mu  = S / (float)M;
        float var = fmaxf(Q / (float)M - mu * mu, 0.f);
        float scale = gamma_[c] / sqrtf(var + EPSBN);
        float shift = beta_[c] - mu * scale;
        ss_out[c] = scale;
        ss_out[C + c] = shift;
    }
}

// ---------------- in-place activation: y = relu(y*scale + shift) ----------------
template<int C>
__global__ void activate_kernel(float* __restrict__ y, const float* __restrict__ ss, int total)
{
    int i = (blockIdx.x * blockDim.x + threadIdx.x) * 4;
    if (i >= total) return;
    float4 v = *(const float4*)(y + i);
    const int c = i % C;
    v.x = fmaxf(v.x * ss[c + 0] + ss[C + c + 0], 0.f);
    v.y = fmaxf(v.y * ss[c + 1] + ss[C + c + 1], 0.f);
    v.z = fmaxf(v.z * ss[c + 2] + ss[C + c + 2], 0.f);
    v.w = fmaxf(v.w * ss[c + 3] + ss[C + c + 3], 0.f);
    *(float4*)(y + i) = v;
}

// ---------------- final write (activation into out) ----------------
__global__ void writeout_kernel(const float* __restrict__ y, const float* __restrict__ ss,
                                float* __restrict__ out, int total)
{
    int i = (blockIdx.x * blockDim.x + threadIdx.x) * 4;
    if (i >= total) return;
    float4 v = *(const float4*)(y + i);
    int c = i % 96;
    float4 o;
    o.x = fmaxf(v.x * ss[c + 0] + ss[96 + c + 0], 0.f);
    o.y = fmaxf(v.y * ss[c + 1] + ss[96 + c + 1], 0.f);
    o.z = fmaxf(v.z * ss[c + 2] + ss[96 + c + 2], 0.f);
    o.w = fmaxf(v.w * ss[c + 3] + ss[96 + c + 3], 0.f);
    *(float4*)(out + i) = o;
}

// ---------------- host ----------------
extern "C" void kernel_launch(void* const* d_in, const int* in_sizes, int n_in,
                              void* d_out, int out_size, void* d_ws, size_t ws_size,
                              hipStream_t stream)
{
    const float* data   = (const float*)d_in[0];
    const int*   neigh0 = (const int*)d_in[1];
    const int*   child0 = (const int*)d_in[2];
    const int*   neigh1 = (const int*)d_in[3];
    const int*   child1 = (const int*)d_in[4];
    const int*   neigh2 = (const int*)d_in[5];
    const float* w0  = (const float*)d_in[6];
    const float* g0  = (const float*)d_in[7];
    const float* b0  = (const float*)d_in[8];
    const float* wd0 = (const float*)d_in[9];
    const float* gd0 = (const float*)d_in[10];
    const float* bd0 = (const float*)d_in[11];
    const float* w1  = (const float*)d_in[12];
    const float* g1  = (const float*)d_in[13];
    const float* b1  = (const float*)d_in[14];
    const float* wd1 = (const float*)d_in[15];
    const float* gd1 = (const float*)d_in[16];
    const float* bd1 = (const float*)d_in[17];
    const float* wp  = (const float*)d_in[18];
    const float* gp  = (const float*)d_in[19];
    const float* bp  = (const float*)d_in[20];
    float* out = (float*)d_out;

    // header (floats)
    float* wsf = (float*)d_ws;
    int*   counters = (int*)d_ws;              // 5 ints in first 64B
    float* sums0 = wsf + 16;
    float* sums1 = wsf + 64;
    float* sums2 = wsf + 160;
    float* sums3 = wsf + 256;
    float* sums4 = wsf + 448;
    float* ss0 = wsf + 640;
    float* ss1 = wsf + 688;
    float* ss2 = wsf + 784;
    float* ss3 = wsf + 880;
    float* ss4 = wsf + 1072;                   // ends 1264, pad 1280

    // arena (same footprint as round 4)
    float* x0 = wsf + 1280;                    // N0*24 = 6291456
    float* y1 = x0 + (size_t)N0 * 24;          // N1*48 = 1572864
    float* y2 = y1 + (size_t)N1 * 48;          // 1572864
    float* y3 = y2 + (size_t)N1 * 48;          // N2*96 = 393216
    float* y4 = y3 + (size_t)N2 * 96;          // 393216
    float* pscratch = y4 + (size_t)N2 * 96;    // 4718592 floats (max: C uses 3*N1*48; E uses 9*N2*96=3538944)

    hipMemsetAsync(d_ws, 0, 1280 * sizeof(float), stream);

    const size_t s1 = (size_t)N1 * 48;  // partial stride, stages B/C
    const size_t s2 = (size_t)N2 * 96;  // partial stride, stages D/E

    // stage A: data[N0,3] -> x0 raw, stats, in-place activate
    conv_kernel<27, 3, 24, 27, 24, 1, 1, 2, true>
        <<<dim3(N0 / 512, 1, 1), 256, 0, stream>>>(data, neigh0, w0, x0, 0, N0);
    stats_kernel<24, 8, 1, false><<<512, dim3(24, 8), 0, stream>>>(x0, 0, nullptr, N0, g0, b0, sums0, &counters[0], ss0);
    activate_kernel<24><<<(N0 * 24 / 4 + 255) / 256, 256, 0, stream>>>(x0, ss0, N0 * 24);

    // stage B: x0 -> y1, k-split 2
    conv_kernel<8, 24, 48, 4, 24, 2, 2, 2, false>
        <<<dim3(N1 / 512, 2, 2), 256, 0, stream>>>(x0, child0, wd0, pscratch, s1, N1);
    stats_kernel<48, 8, 2, true><<<128, dim3(48, 8), 0, stream>>>(pscratch, s1, y1, N1, gd0, bd0, sums1, &counters[1], ss1);
    activate_kernel<48><<<(N1 * 48 / 4 + 255) / 256, 256, 0, stream>>>(y1, ss1, N1 * 48);

    // stage C: y1(act) -> y2, k-split 3
    conv_kernel<27, 48, 48, 9, 24, 3, 2, 2, false>
        <<<dim3(N1 / 512, 3, 2), 256, 0, stream>>>(y1, neigh1, w1, pscratch, s1, N1);
    stats_kernel<48, 8, 3, true><<<128, dim3(48, 8), 0, stream>>>(pscratch, s1, y2, N1, g1, b1, sums2, &counters[2], ss2);
    activate_kernel<48><<<(N1 * 48 / 4 + 255) / 256, 256, 0, stream>>>(y2, ss2, N1 * 48);

    // stage D: y2(act) -> y3, k-split 8
    conv_kernel<8, 48, 96, 1, 24, 8, 4, 2, false>
        <<<dim3(N2 / 512, 8, 4), 256, 0, stream>>>(y2, child1, wd1, pscratch, s2, N2);
    stats_kernel<96, 4, 8, true><<<64, dim3(96, 4), 0, stream>>>(pscratch, s2, y3, N2, gd1, bd1, sums3, &counters[3], ss3);
    activate_kernel<96><<<(N2 * 96 / 4 + 255) / 256, 256, 0, stream>>>(y3, ss3, N2 * 96);

    // stage E: y3(act) -> y4, k-split 9
    conv_kernel<27, 96, 96, 3, 24, 9, 4, 2, false>
        <<<dim3(N2 / 512, 9, 4), 256, 0, stream>>>(y3, neigh2, wp, pscratch, s2, N2);
    stats_kernel<96, 4, 9, true><<<64, dim3(96, 4), 0, stream>>>(pscratch, s2, y4, N2, gp, bp, sums4, &counters[4], ss4);

    // final normalize + relu -> out
    writeout_kernel<<<(N2 * 96 / 4 + 255) / 256, 256, 0, stream>>>(y4, ss4, out, N2 * 96);

    (void)in_sizes; (void)n_in; (void)out_size; (void)ws_size;
}

// Round 6
// 526.098 us; speedup vs baseline: 1.0131x; 1.0131x over previous
//
#include <hip/hip_runtime.h>

// ---------------- problem constants ----------------
#define N0 262144
#define N1 32768
#define N2 4096
#define EPSBN 1e-5f

typedef unsigned short ush_t;

union ufcast { unsigned int u; float f; };
__device__ __forceinline__ float bflo(unsigned int p) { ufcast x; x.u = p << 16;          return x.f; }
__device__ __forceinline__ float bfhi(unsigned int p) { ufcast x; x.u = p & 0xffff0000u; return x.f; }
__device__ __forceinline__ ush_t f2bf(float f) {
    ufcast x; x.f = f;
    unsigned int u = x.u + 0x7fffu + ((x.u >> 16) & 1u);
    return (ush_t)(u >> 16);
}

// ---------------- conv kernel (gather-GEMM; x is bf16, already activated) ----------------
// CINP = padded row stride of x in bf16 elements.
template<int K, int CIN, int CINP, int COUT, int TAPS, int DTILE, int KG, int DG>
__global__ __launch_bounds__(256) void conv_kernel(
    const ush_t* __restrict__ x,         // [Nin, CINP] bf16
    const int*   __restrict__ neigh,     // [M, K]
    const float* __restrict__ W,         // [K, CIN, COUT] f32
    float*       __restrict__ yout,      // KG==1: [M,COUT]; KG>1: partial base
    size_t       ystride,
    int M)
{
    static_assert(K == TAPS * KG, "k split");
    static_assert(COUT == DTILE * DG, "d split");
    constexpr int WSZ = TAPS * CIN * DTILE;
    __shared__ __align__(16) float Wl[WSZ];

    const int tid = threadIdx.x;
    const int kg = blockIdx.y, dg = blockIdx.z;

    for (int i4 = tid; i4 < WSZ / 4; i4 += 256) {
        const int d4 = i4 % (DTILE / 4);
        const int rc = i4 / (DTILE / 4);            // t*CIN + c
        const float4* src = (const float4*)(W + ((size_t)kg * TAPS * CIN + rc) * COUT + dg * DTILE);
        ((float4*)Wl)[i4] = src[d4];
    }
    __syncthreads();

    const int m = blockIdx.x * 256 + tid;
    if (m >= M) return;

    float acc[DTILE];
#pragma unroll
    for (int d = 0; d < DTILE; ++d) acc[d] = 0.f;

    if constexpr (CIN == 3) {
        // stage A: CINP==4, one uint2 (4 bf16) per tap; batch 9 taps
        for (int tg = 0; tg < TAPS; tg += 9) {
            int id[9];
#pragma unroll
            for (int u = 0; u < 9; ++u) id[u] = neigh[(size_t)m * K + tg + u];
            uint2 xv[9];
#pragma unroll
            for (int u = 0; u < 9; ++u) xv[u] = ((const uint2*)x)[id[u]];
#pragma unroll
            for (int u = 0; u < 9; ++u) {
                const float a0 = bflo(xv[u].x);
                const float a1 = bfhi(xv[u].x);
                const float a2 = bflo(xv[u].y);
                const int t = tg + u;
#pragma unroll
                for (int c = 0; c < 3; ++c) {
                    const float a = (c == 0) ? a0 : (c == 1) ? a1 : a2;
                    const float4* wrow = (const float4*)&Wl[(t * 3 + c) * DTILE];
#pragma unroll
                    for (int d4 = 0; d4 < DTILE / 4; ++d4) {
                        float4 w = wrow[d4];
                        acc[4 * d4 + 0] += a * w.x;
                        acc[4 * d4 + 1] += a * w.y;
                        acc[4 * d4 + 2] += a * w.z;
                        acc[4 * d4 + 3] += a * w.w;
                    }
                }
            }
        }
    } else {
        int idxs[TAPS];
        const int* np = neigh + (size_t)m * K + kg * TAPS;
#pragma unroll
        for (int t = 0; t < TAPS; ++t) idxs[t] = np[t];

        constexpr int CHUNKV = (CIN == 24) ? 3 : 6;   // uint4 (8 bf16) staging regs
        constexpr int CHUNK = CHUNKV * 8;
        for (int t = 0; t < TAPS; ++t) {
            const uint4* xp = (const uint4*)(x + (size_t)idxs[t] * CINP);
#pragma unroll
            for (int cc = 0; cc < CIN / CHUNK; ++cc) {
                uint4 xv[CHUNKV];
#pragma unroll
                for (int j = 0; j < CHUNKV; ++j) xv[j] = xp[cc * CHUNKV + j];
#pragma unroll
                for (int j = 0; j < CHUNKV; ++j) {
                    const unsigned int wds[4] = {xv[j].x, xv[j].y, xv[j].z, xv[j].w};
#pragma unroll
                    for (int wq = 0; wq < 4; ++wq) {
                        const int c0 = cc * CHUNK + j * 8 + wq * 2;
                        const float a0 = bflo(wds[wq]);
                        const float a1 = bfhi(wds[wq]);
                        const float4* w0r = (const float4*)&Wl[(t * CIN + c0 + 0) * DTILE];
                        const float4* w1r = (const float4*)&Wl[(t * CIN + c0 + 1) * DTILE];
#pragma unroll
                        for (int d4 = 0; d4 < DTILE / 4; ++d4) {
                            float4 w0 = w0r[d4], w1 = w1r[d4];
                            acc[4 * d4 + 0] += a0 * w0.x + a1 * w1.x;
                            acc[4 * d4 + 1] += a0 * w0.y + a1 * w1.y;
                            acc[4 * d4 + 2] += a0 * w0.z + a1 * w1.z;
                            acc[4 * d4 + 3] += a0 * w0.w + a1 * w1.w;
                        }
                    }
                }
            }
        }
    }

    float* yo = (KG > 1)
        ? yout + (size_t)kg * ystride + (size_t)m * COUT + dg * DTILE
        : yout + (size_t)m * COUT + dg * DTILE;
#pragma unroll
    for (int d4 = 0; d4 < DTILE / 4; ++d4) {
        ((float4*)yo)[d4] = make_float4(acc[4 * d4 + 0], acc[4 * d4 + 1],
                                        acc[4 * d4 + 2], acc[4 * d4 + 3]);
    }
}

// ---------------- stats: sum P partials -> yfull f32, column sum/sumsq, fused finalize ----------------
template<int C, int R, int P, bool WRITE_Y>
__global__ void stats_kernel(const float* __restrict__ part, size_t pstride,
                             float* __restrict__ yfull, int M,
                             const float* __restrict__ gamma_, const float* __restrict__ beta_,
                             float* __restrict__ sums, int* __restrict__ counter,
                             float* __restrict__ ss_out)
{
    __shared__ float ls[R][C];
    __shared__ float lq[R][C];
    __shared__ int lastflag;

    const int c = threadIdx.x;
    const int ty = threadIdx.y;

    float s = 0.f, q = 0.f;
    for (int r = blockIdx.x * R + ty; r < M; r += gridDim.x * R) {
        const size_t off = (size_t)r * C + c;
        float v = 0.f;
#pragma unroll
        for (int p = 0; p < P; ++p) v += part[(size_t)p * pstride + off];
        if constexpr (WRITE_Y) yfull[off] = v;
        s += v;
        q += v * v;
    }
    ls[ty][c] = s; lq[ty][c] = q;
    __syncthreads();
    if (ty == 0) {
#pragma unroll
        for (int r = 1; r < R; ++r) { s += ls[r][c]; q += lq[r][c]; }
        atomicAdd(&sums[c], s);
        atomicAdd(&sums[C + c], q);
    }
    __syncthreads();
    if (c == 0 && ty == 0) {
        __threadfence();
        int p = __hip_atomic_fetch_add(counter, 1, __ATOMIC_ACQ_REL, __HIP_MEMORY_SCOPE_AGENT);
        lastflag = (p == (int)gridDim.x - 1) ? 1 : 0;
    }
    __syncthreads();
    if (lastflag && ty == 0) {
        float S = __hip_atomic_load(&sums[c],     __ATOMIC_RELAXED, __HIP_MEMORY_SCOPE_AGENT);
        float Q = __hip_atomic_load(&sums[C + c], __ATOMIC_RELAXED, __HIP_MEMORY_SCOPE_AGENT);
        float mu  = S / (float)M;
        float var = fmaxf(Q / (float)M - mu * mu, 0.f);
        float scale = gamma_[c] / sqrtf(var + EPSBN);
        float shift = beta_[c] - mu * scale;
        ss_out[c] = scale;
        ss_out[C + c] = shift;
    }
}

// ---------------- activation: xb16 = bf16(relu(y*scale + shift)) ----------------
template<int C>
__global__ void activate_kernel(const float* __restrict__ y, const float* __restrict__ ss,
                                ush_t* __restrict__ xb, int total)
{
    int i = (blockIdx.x * blockDim.x + threadIdx.x) * 4;
    if (i >= total) return;
    float4 v = *(const float4*)(y + i);
    const int c = i % C;
    ushort4 o;
    o.x = f2bf(fmaxf(v.x * ss[c + 0] + ss[C + c + 0], 0.f));
    o.y = f2bf(fmaxf(v.y * ss[c + 1] + ss[C + c + 1], 0.f));
    o.z = f2bf(fmaxf(v.z * ss[c + 2] + ss[C + c + 2], 0.f));
    o.w = f2bf(fmaxf(v.w * ss[c + 3] + ss[C + c + 3], 0.f));
    *(ushort4*)(xb + i) = o;
}

// ---------------- prep: pack data [N0,3] f32 -> [N0,4] bf16 ----------------
__global__ void prep_kernel(const float* __restrict__ data, ush_t* __restrict__ xa, int n)
{
    int m = blockIdx.x * blockDim.x + threadIdx.x;
    if (m >= n) return;
    const float* dp = data + (size_t)3 * m;
    unsigned int h0 = f2bf(dp[0]), h1 = f2bf(dp[1]), h2 = f2bf(dp[2]);
    uint2 v; v.x = h0 | (h1 << 16); v.y = h2;
    ((uint2*)xa)[m] = v;
}

// ---------------- final write (f32 out) ----------------
__global__ void writeout_kernel(const float* __restrict__ y, const float* __restrict__ ss,
                                float* __restrict__ out, int total)
{
    int i = (blockIdx.x * blockDim.x + threadIdx.x) * 4;
    if (i >= total) return;
    float4 v = *(const float4*)(y + i);
    int c = i % 96;
    float4 o;
    o.x = fmaxf(v.x * ss[c + 0] + ss[96 + c + 0], 0.f);
    o.y = fmaxf(v.y * ss[c + 1] + ss[96 + c + 1], 0.f);
    o.z = fmaxf(v.z * ss[c + 2] + ss[96 + c + 2], 0.f);
    o.w = fmaxf(v.w * ss[c + 3] + ss[96 + c + 3], 0.f);
    *(float4*)(out + i) = o;
}

// ---------------- host ----------------
extern "C" void kernel_launch(void* const* d_in, const int* in_sizes, int n_in,
                              void* d_out, int out_size, void* d_ws, size_t ws_size,
                              hipStream_t stream)
{
    const float* data   = (const float*)d_in[0];
    const int*   neigh0 = (const int*)d_in[1];
    const int*   child0 = (const int*)d_in[2];
    const int*   neigh1 = (const int*)d_in[3];
    const int*   child1 = (const int*)d_in[4];
    const int*   neigh2 = (const int*)d_in[5];
    const float* w0  = (const float*)d_in[6];
    const float* g0  = (const float*)d_in[7];
    const float* b0  = (const float*)d_in[8];
    const float* wd0 = (const float*)d_in[9];
    const float* gd0 = (const float*)d_in[10];
    const float* bd0 = (const float*)d_in[11];
    const float* w1  = (const float*)d_in[12];
    const float* g1  = (const float*)d_in[13];
    const float* b1  = (const float*)d_in[14];
    const float* wd1 = (const float*)d_in[15];
    const float* gd1 = (const float*)d_in[16];
    const float* bd1 = (const float*)d_in[17];
    const float* wp  = (const float*)d_in[18];
    const float* gp  = (const float*)d_in[19];
    const float* bp  = (const float*)d_in[20];
    float* out = (float*)d_out;

    // header (floats)
    float* wsf = (float*)d_ws;
    int*   counters = (int*)d_ws;
    float* sums0 = wsf + 16;
    float* sums1 = wsf + 64;
    float* sums2 = wsf + 160;
    float* sums3 = wsf + 256;
    float* sums4 = wsf + 448;
    float* ss0 = wsf + 640;
    float* ss1 = wsf + 688;
    float* ss2 = wsf + 784;
    float* ss3 = wsf + 880;
    float* ss4 = wsf + 1072;                   // ends 1264, pad 1280

    // arena with aliasing (total ~46.2 MB):
    // R1 (6291456 f): stage-A raw f32 output, then all k-split partials (max 4718592 f)
    // R2 (1572864 f): y f32 (y1,y2,y3,y4 sequentially)
    // XB (6291456 ush): activated bf16 x (x0b, then y1b, y2b, y3b sequentially)
    // XA (1048576 ush): packed bf16 input [N0,4]
    float* R1 = wsf + 1280;
    float* R2 = R1 + (size_t)6291456;
    ush_t* XB = (ush_t*)(R2 + (size_t)1572864);
    ush_t* XA = XB + (size_t)6291456;

    hipMemsetAsync(d_ws, 0, 1280 * sizeof(float), stream);

    const size_t s1 = (size_t)N1 * 48;
    const size_t s2 = (size_t)N2 * 96;

    // stage A
    prep_kernel<<<N0 / 256, 256, 0, stream>>>(data, XA, N0);
    conv_kernel<27, 3, 4, 24, 27, 24, 1, 1>
        <<<dim3(N0 / 256, 1, 1), 256, 0, stream>>>(XA, neigh0, w0, R1, 0, N0);
    stats_kernel<24, 8, 1, false><<<512, dim3(24, 8), 0, stream>>>(R1, 0, nullptr, N0, g0, b0, sums0, &counters[0], ss0);
    activate_kernel<24><<<(N0 * 24 / 4 + 255) / 256, 256, 0, stream>>>(R1, ss0, XB, N0 * 24);

    // stage B: x0b -> partials(2) -> y1 -> y1b
    conv_kernel<8, 24, 24, 48, 4, 24, 2, 2>
        <<<dim3(N1 / 256, 2, 2), 256, 0, stream>>>(XB, child0, wd0, R1, s1, N1);
    stats_kernel<48, 8, 2, true><<<128, dim3(48, 8), 0, stream>>>(R1, s1, R2, N1, gd0, bd0, sums1, &counters[1], ss1);
    activate_kernel<48><<<(N1 * 48 / 4 + 255) / 256, 256, 0, stream>>>(R2, ss1, XB, N1 * 48);

    // stage C: y1b -> partials(3) -> y2 -> y2b
    conv_kernel<27, 48, 48, 48, 9, 24, 3, 2>
        <<<dim3(N1 / 256, 3, 2), 256, 0, stream>>>(XB, neigh1, w1, R1, s1, N1);
    stats_kernel<48, 8, 3, true><<<128, dim3(48, 8), 0, stream>>>(R1, s1, R2, N1, g1, b1, sums2, &counters[2], ss2);
    activate_kernel<48><<<(N1 * 48 / 4 + 255) / 256, 256, 0, stream>>>(R2, ss2, XB, N1 * 48);

    // stage D: y2b -> partials(8) -> y3 -> y3b
    conv_kernel<8, 48, 48, 96, 1, 24, 8, 4>
        <<<dim3(N2 / 256, 8, 4), 256, 0, stream>>>(XB, child1, wd1, R1, s2, N2);
    stats_kernel<96, 4, 8, true><<<64, dim3(96, 4), 0, stream>>>(R1, s2, R2, N2, gd1, bd1, sums3, &counters[3], ss3);
    activate_kernel<96><<<(N2 * 96 / 4 + 255) / 256, 256, 0, stream>>>(R2, ss3, XB, N2 * 96);

    // stage E: y3b -> partials(9) -> y4
    conv_kernel<27, 96, 96, 96, 3, 24, 9, 4>
        <<<dim3(N2 / 256, 9, 4), 256, 0, stream>>>(XB, neigh2, wp, R1, s2, N2);
    stats_kernel<96, 4, 9, true><<<64, dim3(96, 4), 0, stream>>>(R1, s2, R2, N2, gp, bp, sums4, &counters[4], ss4);

    // final normalize + relu -> out
    writeout_kernel<<<(N2 * 96 / 4 + 255) / 256, 256, 0, stream>>>(R2, ss4, out, N2 * 96);

    (void)in_sizes; (void)n_in; (void)out_size; (void)ws_size;
}

// Round 7
// 337.258 us; speedup vs baseline: 1.5803x; 1.5599x over previous
//
#include <hip/hip_runtime.h>

// ---------------- problem constants ----------------
#define N0 262144
#define N1 32768
#define N2 4096
#define EPSBN 1e-5f

typedef unsigned short ush_t;
typedef __bf16 bf16x8 __attribute__((ext_vector_type(8)));
typedef float  f32x4  __attribute__((ext_vector_type(4)));

union ufcast { unsigned int u; float f; };
__device__ __forceinline__ ush_t f2bf(float f) {
    ufcast x; x.f = f;
    unsigned int u = x.u + 0x7fffu + ((x.u >> 16) & 1u);
    return (ush_t)(u >> 16);
}
__device__ __forceinline__ bf16x8 as_bf8(uint4 u) {
    union { uint4 u; bf16x8 b; } x; x.u = u; return x.b;
}

// ---------------- weight prep: W[K][CIN][COUT] f32 -> Wb[chunk][COUTP][32] bf16 (transposed, padded) ----------------
template<int K, int CIN, int CINP_W, int COUT, int COUTP, int NCH>
__device__ __forceinline__ void prep_stage(const float* __restrict__ W, ush_t* __restrict__ Wb, int e) {
    // e in [0, NCH*COUTP*32)
    const int k  = e & 31;
    const int n  = (e >> 5) % COUTP;
    const int ch = e / (32 * COUTP);
    const int kp = ch * 32 + k;
    const int t  = kp / CINP_W;
    const int c  = kp % CINP_W;
    float v = 0.f;
    if (t < K && c < CIN && n < COUT) v = W[((size_t)t * CIN + c) * COUT + n];
    Wb[e] = f2bf(v);
}

__global__ __launch_bounds__(256) void prep_weights(
    const float* w0, const float* wd0, const float* w1, const float* wd1, const float* wp,
    ush_t* wbA, ush_t* wbB, ush_t* wbC, ush_t* wbD, ush_t* wbE)
{
    const int e = blockIdx.x * 256 + threadIdx.x;
    switch (blockIdx.y) {
        case 0: if (e <   4096) prep_stage<27,  3,  4, 24, 32,  4>(w0,  wbA, e); break;
        case 1: if (e <  12288) prep_stage< 8, 24, 32, 48, 48,  8>(wd0, wbB, e); break;
        case 2: if (e <  82944) prep_stage<27, 48, 64, 48, 48, 54>(w1,  wbC, e); break;
        case 3: if (e <  49152) prep_stage< 8, 48, 64, 96, 96, 16>(wd1, wbD, e); break;
        case 4: if (e < 248832) prep_stage<27, 96, 96, 96, 96, 81>(wp,  wbE, e); break;
    }
}

// ---------------- input prep: data [N0,3] f32 -> XA [N0,4] bf16 (c3 = 0) ----------------
__global__ void prep_input(const float* __restrict__ data, ush_t* __restrict__ xa, int n)
{
    int m = blockIdx.x * blockDim.x + threadIdx.x;
    if (m >= n) return;
    const float* dp = data + (size_t)3 * m;
    unsigned int h0 = f2bf(dp[0]), h1 = f2bf(dp[1]), h2 = f2bf(dp[2]);
    uint2 v; v.x = h0 | (h1 << 16); v.y = h2;   // high half of .y = 0
    ((uint2*)xa)[m] = v;
}

// ---------------- MFMA conv (generic, CINP>=32): no LDS, direct-to-fragment ----------------
// y[m,d] = sum over K-chunks of A(gathered) x Wb.  Grid: (M/64, KG, CG), 256 threads = 4 waves.
template<int K, int CIN, int CINP, int COUT, int COUTP, int NCHT, int KG, int CG>
__global__ __launch_bounds__(256) void mconv(
    const ush_t* __restrict__ xb,     // [Nin, CINP] bf16, channel-padded with zeros
    const int*   __restrict__ neigh,  // [M, K]
    const ush_t* __restrict__ Wb,     // [NCHT][COUTP][32] bf16
    float*       __restrict__ yout,   // KG==1: [M,COUT]; else partial base
    size_t       ystride, int M)
{
    constexpr int NCH = NCHT / KG;
    constexpr int NCT = (COUTP / 16) / CG;
    constexpr int CPT = CINP / 32;
    const int lane = threadIdx.x & 63;
    const int wave = threadIdx.x >> 6;
    const int quad = lane >> 4, l15 = lane & 15;
    const int kg = blockIdx.y, cg = blockIdx.z;
    const int rowA = blockIdx.x * 64 + wave * 16 + l15;     // A-fragment row

    f32x4 acc[NCT] = {};

#pragma unroll
    for (int ci = 0; ci < NCH; ++ci) {
        const int ch  = kg * NCH + ci;
        const int t   = ch / CPT;
        const int sub = ch % CPT;
        const int idx = neigh[(size_t)rowA * K + t];
        const uint4 au = *(const uint4*)(xb + (size_t)idx * CINP + sub * 32 + quad * 8);
        const bf16x8 af = as_bf8(au);
#pragma unroll
        for (int ct = 0; ct < NCT; ++ct) {
            const int n = (cg * NCT + ct) * 16 + l15;
            const uint4 bu = *(const uint4*)(Wb + ((size_t)ch * COUTP + n) * 32 + quad * 8);
            acc[ct] = __builtin_amdgcn_mfma_f32_16x16x32_bf16(af, as_bf8(bu), acc[ct], 0, 0, 0);
        }
    }

    float* yo = yout + (size_t)kg * ystride;
#pragma unroll
    for (int ct = 0; ct < NCT; ++ct) {
        const int col = (cg * NCT + ct) * 16 + l15;
        if (COUTP != COUT && col >= COUT) continue;
#pragma unroll
        for (int r = 0; r < 4; ++r) {
            const int rr = blockIdx.x * 64 + wave * 16 + quad * 4 + r;   // D row = quad*4 + reg
            yo[(size_t)rr * COUT + col] = acc[ct][r];
        }
    }
}

// ---------------- MFMA conv, stage A (CINP=4: one K32-chunk spans 8 taps) ----------------
__global__ __launch_bounds__(256) void mconvA(
    const ush_t* __restrict__ xa,     // [N0, 4] bf16
    const int*   __restrict__ neigh,  // [N0, 27]
    const ush_t* __restrict__ Wb,     // [4][32][32] bf16 (rows k'>=108 are zero)
    float*       __restrict__ y)      // [N0, 24]
{
    const int lane = threadIdx.x & 63;
    const int wave = threadIdx.x >> 6;
    const int quad = lane >> 4, l15 = lane & 15;
    const int rowA = blockIdx.x * 64 + wave * 16 + l15;

    f32x4 acc[2] = {};

#pragma unroll
    for (int ch = 0; ch < 4; ++ch) {
        const int tA = ch * 8 + quad * 2;            // this lane's two taps
        const int t0 = (tA     < 27) ? tA     : 26;  // clamp: Wb rows zero past k'=108
        const int t1 = (tA + 1 < 27) ? tA + 1 : 26;
        const int iA = neigh[(size_t)rowA * 27 + t0];
        const int iB = neigh[(size_t)rowA * 27 + t1];
        const uint2 lo = *(const uint2*)(xa + (size_t)iA * 4);
        const uint2 hi = *(const uint2*)(xa + (size_t)iB * 4);
        const uint4 au = make_uint4(lo.x, lo.y, hi.x, hi.y);
        const bf16x8 af = as_bf8(au);
#pragma unroll
        for (int ct = 0; ct < 2; ++ct) {
            const int n = ct * 16 + l15;
            const uint4 bu = *(const uint4*)(Wb + ((size_t)ch * 32 + n) * 32 + quad * 8);
            acc[ct] = __builtin_amdgcn_mfma_f32_16x16x32_bf16(af, as_bf8(bu), acc[ct], 0, 0, 0);
        }
    }

#pragma unroll
    for (int ct = 0; ct < 2; ++ct) {
        const int col = ct * 16 + l15;
        if (col >= 24) continue;
#pragma unroll
        for (int r = 0; r < 4; ++r) {
            const int rr = blockIdx.x * 64 + wave * 16 + quad * 4 + r;
            y[(size_t)rr * 24 + col] = acc[ct][r];
        }
    }
}

// ---------------- stats: sum P partials -> yfull f32, column sum/sumsq, fused finalize ----------------
template<int C, int R, int P, bool WRITE_Y>
__global__ void stats_kernel(const float* __restrict__ part, size_t pstride,
                             float* __restrict__ yfull, int M,
                             const float* __restrict__ gamma_, const float* __restrict__ beta_,
                             float* __restrict__ sums, int* __restrict__ counter,
                             float* __restrict__ ss_out)
{
    __shared__ float ls[R][C];
    __shared__ float lq[R][C];
    __shared__ int lastflag;

    const int c = threadIdx.x;
    const int ty = threadIdx.y;

    float s = 0.f, q = 0.f;
    for (int r = blockIdx.x * R + ty; r < M; r += gridDim.x * R) {
        const size_t off = (size_t)r * C + c;
        float v = 0.f;
#pragma unroll
        for (int p = 0; p < P; ++p) v += part[(size_t)p * pstride + off];
        if constexpr (WRITE_Y) yfull[off] = v;
        s += v;
        q += v * v;
    }
    ls[ty][c] = s; lq[ty][c] = q;
    __syncthreads();
    if (ty == 0) {
#pragma unroll
        for (int r = 1; r < R; ++r) { s += ls[r][c]; q += lq[r][c]; }
        atomicAdd(&sums[c], s);
        atomicAdd(&sums[C + c], q);
    }
    __syncthreads();
    if (c == 0 && ty == 0) {
        __threadfence();
        int p = __hip_atomic_fetch_add(counter, 1, __ATOMIC_ACQ_REL, __HIP_MEMORY_SCOPE_AGENT);
        lastflag = (p == (int)gridDim.x - 1) ? 1 : 0;
    }
    __syncthreads();
    if (lastflag && ty == 0) {
        float S = __hip_atomic_load(&sums[c],     __ATOMIC_RELAXED, __HIP_MEMORY_SCOPE_AGENT);
        float Q = __hip_atomic_load(&sums[C + c], __ATOMIC_RELAXED, __HIP_MEMORY_SCOPE_AGENT);
        float mu  = S / (float)M;
        float var = fmaxf(Q / (float)M - mu * mu, 0.f);
        float scale = gamma_[c] / sqrtf(var + EPSBN);
        float shift = beta_[c] - mu * scale;
        ss_out[c] = scale;
        ss_out[C + c] = shift;
    }
}

// ---------------- activation: XB[r, 0..CP) = bf16(relu(y*scale+shift)), zeros in pad cols ----------------
template<int C, int CP>
__global__ void activate_kernel(const float* __restrict__ y, const float* __restrict__ ss,
                                ush_t* __restrict__ xb, int totalP)   // totalP = N*CP
{
    int i = (blockIdx.x * blockDim.x + threadIdx.x) * 4;
    if (i >= totalP) return;
    const int c = i % CP;
    ushort4 o;
    if (CP != C && c >= C) {
        o.x = o.y = o.z = o.w = 0;
    } else {
        const int r = i / CP;
        float4 v = *(const float4*)(y + (size_t)r * C + c);
        o.x = f2bf(fmaxf(v.x * ss[c + 0] + ss[C + c + 0], 0.f));
        o.y = f2bf(fmaxf(v.y * ss[c + 1] + ss[C + c + 1], 0.f));
        o.z = f2bf(fmaxf(v.z * ss[c + 2] + ss[C + c + 2], 0.f));
        o.w = f2bf(fmaxf(v.w * ss[c + 3] + ss[C + c + 3], 0.f));
    }
    *(ushort4*)(xb + i) = o;
}

// ---------------- final write (f32 out) ----------------
__global__ void writeout_kernel(const float* __restrict__ y, const float* __restrict__ ss,
                                float* __restrict__ out, int total)
{
    int i = (blockIdx.x * blockDim.x + threadIdx.x) * 4;
    if (i >= total) return;
    float4 v = *(const float4*)(y + i);
    int c = i % 96;
    float4 o;
    o.x = fmaxf(v.x * ss[c + 0] + ss[96 + c + 0], 0.f);
    o.y = fmaxf(v.y * ss[c + 1] + ss[96 + c + 1], 0.f);
    o.z = fmaxf(v.z * ss[c + 2] + ss[96 + c + 2], 0.f);
    o.w = fmaxf(v.w * ss[c + 3] + ss[96 + c + 3], 0.f);
    *(float4*)(out + i) = o;
}

// ---------------- host ----------------
extern "C" void kernel_launch(void* const* d_in, const int* in_sizes, int n_in,
                              void* d_out, int out_size, void* d_ws, size_t ws_size,
                              hipStream_t stream)
{
    const float* data   = (const float*)d_in[0];
    const int*   neigh0 = (const int*)d_in[1];
    const int*   child0 = (const int*)d_in[2];
    const int*   neigh1 = (const int*)d_in[3];
    const int*   child1 = (const int*)d_in[4];
    const int*   neigh2 = (const int*)d_in[5];
    const float* w0  = (const float*)d_in[6];
    const float* g0  = (const float*)d_in[7];
    const float* b0  = (const float*)d_in[8];
    const float* wd0 = (const float*)d_in[9];
    const float* gd0 = (const float*)d_in[10];
    const float* bd0 = (const float*)d_in[11];
    const float* w1  = (const float*)d_in[12];
    const float* g1  = (const float*)d_in[13];
    const float* b1  = (const float*)d_in[14];
    const float* wd1 = (const float*)d_in[15];
    const float* gd1 = (const float*)d_in[16];
    const float* bd1 = (const float*)d_in[17];
    const float* wp  = (const float*)d_in[18];
    const float* gp  = (const float*)d_in[19];
    const float* bp  = (const float*)d_in[20];
    float* out = (float*)d_out;

    // header (floats)
    float* wsf = (float*)d_ws;
    int*   counters = (int*)d_ws;
    float* sums0 = wsf + 16;
    float* sums1 = wsf + 64;
    float* sums2 = wsf + 160;
    float* sums3 = wsf + 256;
    float* sums4 = wsf + 448;
    float* ss0 = wsf + 640;
    float* ss1 = wsf + 688;
    float* ss2 = wsf + 784;
    float* ss3 = wsf + 880;
    float* ss4 = wsf + 1072;                       // ends 1264, pad 1280

    // arena (f32 units), total 14,812,416 f = 59.25 MB
    float* YF   = wsf + 1280;                      // 6291456 f : y0 [N0,24]; later y1/y2 [N1,48], y3/y4 [N2,96]
    float* PART = YF + (size_t)6291456;            // 3538944 f : k-split partials (max 9 x N2 x 96)
    ush_t* XB   = (ush_t*)(PART + (size_t)3538944);// 8388608 ush: x0b [N0,32]; later y1b/y2b [N1,64], y3b [N2,96]
    ush_t* XA   = XB + (size_t)8388608;            // 1048576 ush: packed input [N0,4]
    ush_t* WB   = XA + (size_t)1048576;            //  524288 ush: prepped weights (397312 used)

    ush_t* wbA = WB;
    ush_t* wbB = WB + 4096;
    ush_t* wbC = WB + 16384;
    ush_t* wbD = WB + 99328;
    ush_t* wbE = WB + 148480;

    hipMemsetAsync(d_ws, 0, 1280 * sizeof(float), stream);

    const size_t s1 = (size_t)N1 * 48;
    const size_t s2 = (size_t)N2 * 96;

    // weight + input prep
    prep_weights<<<dim3(972, 5), 256, 0, stream>>>(w0, wd0, w1, wd1, wp, wbA, wbB, wbC, wbD, wbE);
    prep_input<<<N0 / 256, 256, 0, stream>>>(data, XA, N0);

    // stage A: XA -> YF(y0) ; stats ; activate -> XB (x0b, [N0,32])
    mconvA<<<N0 / 64, 256, 0, stream>>>(XA, neigh0, wbA, YF);
    stats_kernel<24, 8, 1, false><<<512, dim3(24, 8), 0, stream>>>(YF, 0, nullptr, N0, g0, b0, sums0, &counters[0], ss0);
    activate_kernel<24, 32><<<N0 * 32 / 4 / 256, 256, 0, stream>>>(YF, ss0, XB, N0 * 32);

    // stage B: XB -> PART(2) ; stats->YF(y1) ; activate -> XB (y1b, [N1,64])
    mconv<8, 24, 32, 48, 48, 8, 2, 1><<<dim3(N1 / 64, 2, 1), 256, 0, stream>>>(XB, child0, wbB, PART, s1, N1);
    stats_kernel<48, 8, 2, true><<<128, dim3(48, 8), 0, stream>>>(PART, s1, YF, N1, gd0, bd0, sums1, &counters[1], ss1);
    activate_kernel<48, 64><<<N1 * 64 / 4 / 256, 256, 0, stream>>>(YF, ss1, XB, N1 * 64);

    // stage C: XB -> PART(2) ; stats->YF(y2) ; activate -> XB (y2b, [N1,64])
    mconv<27, 48, 64, 48, 48, 54, 2, 1><<<dim3(N1 / 64, 2, 1), 256, 0, stream>>>(XB, neigh1, wbC, PART, s1, N1);
    stats_kernel<48, 8, 2, true><<<128, dim3(48, 8), 0, stream>>>(PART, s1, YF, N1, g1, b1, sums2, &counters[2], ss2);
    activate_kernel<48, 64><<<N1 * 64 / 4 / 256, 256, 0, stream>>>(YF, ss2, XB, N1 * 64);

    // stage D: XB -> PART(4) ; stats->YF(y3) ; activate -> XB (y3b, [N2,96])
    mconv<8, 48, 64, 96, 96, 16, 4, 3><<<dim3(N2 / 64, 4, 3), 256, 0, stream>>>(XB, child1, wbD, PART, s2, N2);
    stats_kernel<96, 4, 4, true><<<64, dim3(96, 4), 0, stream>>>(PART, s2, YF, N2, gd1, bd1, sums3, &counters[3], ss3);
    activate_kernel<96, 96><<<N2 * 96 / 4 / 256, 256, 0, stream>>>(YF, ss3, XB, N2 * 96);

    // stage E: XB -> PART(9) ; stats->YF(y4)
    mconv<27, 96, 96, 96, 96, 81, 9, 2><<<dim3(N2 / 64, 9, 2), 256, 0, stream>>>(XB, neigh2, wbE, PART, s2, N2);
    stats_kernel<96, 4, 9, true><<<64, dim3(96, 4), 0, stream>>>(PART, s2, YF, N2, gp, bp, sums4, &counters[4], ss4);

    // final normalize + relu -> out
    writeout_kernel<<<N2 * 96 / 4 / 256, 256, 0, stream>>>(YF, ss4, out, N2 * 96);

    (void)in_sizes; (void)n_in; (void)out_size; (void)ws_size;
}